// Round 1
// baseline (56.621 us; speedup 1.0000x reference)
//
#include <hip/hip_runtime.h>

// TimeNormalization: EMA scan over time + normalization.
//   s_t = 0.1*[x, x^2] + 0.9*s_{t-1}   (per (b,f), scan over t)
//   x_norm = (x - m) / sqrt(v - m^2 + 1e-3)
// Outputs concatenated: x_norm [B,T,F] then final_state [2,B,F].
//
// Parallelization: the 0.9-decay recurrence forgets the past geometrically
// (0.9^128 ~ 1.4e-6), so each T-chunk warms up its state over a 128-step
// halo starting from (0,0). Chunk 0 uses the exact init state. 16 chunks
// of 256 steps -> 512 blocks x 256 threads = 8 waves/CU, memory-bound.

namespace {
constexpr int Bc = 16, Tc = 4096, Fc = 512;
constexpr int CL = 256;          // chunk length
constexpr int KH = 128;          // halo (0.9^128 ~ 1.4e-6 truncation)
constexpr int NCHUNK = Tc / CL;  // 16
constexpr float ALPHA = 0.1f;
constexpr float OMA = 0.9f;
constexpr float EPS = 1e-3f;
}

__global__ __launch_bounds__(256) void tn_kernel(const float* __restrict__ x,
                                                 const float* __restrict__ state,
                                                 float* __restrict__ out) {
    const int bid = blockIdx.x;            // grid = B * NCHUNK * 2 = 512
    const int fh = bid & 1;                // which half of F
    const int chunk = (bid >> 1) & (NCHUNK - 1);
    const int b = bid >> 5;                // 2*NCHUNK = 32
    const int f = fh * 256 + threadIdx.x;  // feature index (coalesced across lanes)
    const int t0 = chunk * CL;

    const size_t base = ((size_t)b * Tc + t0) * Fc + f;
    const float* xp = x + base;

    float s_m, s_v;
    if (chunk == 0) {
        // exact initial state: state[0,b,f] (mean), state[1,b,f] (mean-square)
        s_m = state[b * Fc + f];
        s_v = state[Bc * Fc + b * Fc + f];
    } else {
        // halo warm-up from (0,0); truncated history contributes <= 0.9^KH
        s_m = 0.f;
        s_v = 0.f;
        const float* wp = xp - (size_t)KH * Fc;
#pragma unroll 8
        for (int i = 0; i < KH; ++i) {
            float xv = wp[(size_t)i * Fc];
            float px = ALPHA * xv;
            s_m = fmaf(OMA, s_m, px);
            s_v = fmaf(OMA, s_v, px * xv);
        }
    }

    float* op = out + base;
#pragma unroll 8
    for (int i = 0; i < CL; ++i) {
        float xv = xp[(size_t)i * Fc];
        float px = ALPHA * xv;
        s_m = fmaf(OMA, s_m, px);
        s_v = fmaf(OMA, s_v, px * xv);
        float var = fmaf(-s_m, s_m, s_v);          // v - m^2  (>= 0 analytically)
        op[(size_t)i * Fc] = (xv - s_m) * rsqrtf(var + EPS);
    }

    if (chunk == NCHUNK - 1) {
        // final_state [2,B,F] appended after x_norm
        const size_t so = (size_t)Bc * Tc * Fc;
        out[so + (size_t)b * Fc + f] = s_m;
        out[so + (size_t)Bc * Fc + (size_t)b * Fc + f] = s_v;
    }
}

extern "C" void kernel_launch(void* const* d_in, const int* in_sizes, int n_in,
                              void* d_out, int out_size, void* d_ws, size_t ws_size,
                              hipStream_t stream) {
    const float* x = (const float*)d_in[0];      // [B,T,F] f32
    const float* st = (const float*)d_in[1];     // [2,B,F] f32
    float* out = (float*)d_out;                  // x_norm + final_state

    dim3 grid(Bc * NCHUNK * 2);
    dim3 block(256);
    tn_kernel<<<grid, block, 0, stream>>>(x, st, out);
}